// Round 1
// baseline (989.412 us; speedup 1.0000x reference)
//
#include <hip/hip_runtime.h>
#include <math.h>

#define BB 4
#define SS 1024
#define HH 12
#define DD 32
#define HIDDEN 768
#define AHS 384
#define RQ 8
#define HEAD_ELEMS (SS*DD)      // 32768
#define CTX_ELEMS (BB*SS*AHS)   // 1572864

__device__ __forceinline__ float clampf(float x, float lo, float hi){ return fminf(fmaxf(x, lo), hi); }

// ---------------------------------------------------------------------------
// Kernel 1: fused QKV projection.  C = X @ W^T + b for 4 weight matrices,
// treated as one [4096 x 1536] GEMM. q,v stored [BH,S,D]; k1,k2 stored
// TRANSPOSED [BH,D,S] so attention k-loads are lane-coalesced.
// ---------------------------------------------------------------------------
__global__ __launch_bounds__(256)
void proj_kernel(const float* __restrict__ X,
                 const float* __restrict__ W0, const float* __restrict__ b0,
                 const float* __restrict__ W1, const float* __restrict__ b1,
                 const float* __restrict__ W2, const float* __restrict__ b2,
                 const float* __restrict__ W3, const float* __restrict__ b3,
                 float* __restrict__ qo, float* __restrict__ k1o,
                 float* __restrict__ k2o, float* __restrict__ vo)
{
    const int BM = 64, BN = 64, BK = 16;
    __shared__ float Xs[16][68];   // [k][m], +4 pad
    __shared__ float Wsh[16][68];  // [k][n]
    int t  = threadIdx.x;
    int m0 = blockIdx.x * BM;
    int n0 = blockIdx.y * BN;           // 64 | 384, so one matrix per block
    int mat = n0 / AHS;
    int c0  = n0 % AHS;
    const float* W    = (mat==0) ? W0 : (mat==1) ? W1 : (mat==2) ? W2 : W3;
    const float* bias = (mat==0) ? b0 : (mat==1) ? b1 : (mat==2) ? b2 : b3;

    int tx = t & 15, ty = t >> 4;       // 16x16 threads, 4x4 micro-tile
    int lr = t >> 2;                    // 0..63 load row
    int lc = (t & 3) << 2;              // 0,4,8,12 load col quad

    float acc[4][4];
    #pragma unroll
    for (int i = 0; i < 4; i++)
        #pragma unroll
        for (int j = 0; j < 4; j++) acc[i][j] = 0.f;

    for (int k0 = 0; k0 < HIDDEN; k0 += BK) {
        float4 xa = *(const float4*)(X + (m0 + lr) * HIDDEN + k0 + lc);
        float4 wa = *(const float4*)(W + (c0 + lr) * HIDDEN + k0 + lc);
        __syncthreads();
        Xs[lc+0][lr] = xa.x; Xs[lc+1][lr] = xa.y; Xs[lc+2][lr] = xa.z; Xs[lc+3][lr] = xa.w;
        Wsh[lc+0][lr] = wa.x; Wsh[lc+1][lr] = wa.y; Wsh[lc+2][lr] = wa.z; Wsh[lc+3][lr] = wa.w;
        __syncthreads();
        #pragma unroll
        for (int kk = 0; kk < BK; kk++) {
            float a[4], w4[4];
            *(float4*)a  = *(const float4*)&Xs[kk][ty << 2];
            *(float4*)w4 = *(const float4*)&Wsh[kk][tx << 2];
            #pragma unroll
            for (int i = 0; i < 4; i++)
                #pragma unroll
                for (int j = 0; j < 4; j++)
                    acc[i][j] = fmaf(a[i], w4[j], acc[i][j]);
        }
    }

    #pragma unroll
    for (int i = 0; i < 4; i++) {
        int row = m0 + (ty << 2) + i;
        int b_  = row >> 10;            // row / 1024
        int s   = row & 1023;
        #pragma unroll
        for (int j = 0; j < 4; j++) {
            int c = c0 + (tx << 2) + j;
            int h = c >> 5, d = c & 31;
            int bh = b_ * HH + h;
            float val = acc[i][j] + bias[c];
            if (mat == 0)      qo [(bh * SS + s) * DD + d] = val;
            else if (mat == 1) k1o[(bh * DD + d) * SS + s] = val;
            else if (mat == 2) k2o[(bh * DD + d) * SS + s] = val;
            else               vo [(bh * SS + s) * DD + d] = val;
        }
    }
}

// ---------------------------------------------------------------------------
// Kernel 2: per-row squared norms of k1,k2 from the transposed layout.
// ---------------------------------------------------------------------------
__global__ __launch_bounds__(256)
void norms_kernel(const float* __restrict__ k1T, const float* __restrict__ k2T,
                  float* __restrict__ n1, float* __restrict__ n2)
{
    int bh = blockIdx.y;
    int s  = blockIdx.x * 256 + threadIdx.x;
    const float* p1 = k1T + bh * HEAD_ELEMS + s;
    const float* p2 = k2T + bh * HEAD_ELEMS + s;
    float a1 = 0.f, a2 = 0.f;
    #pragma unroll
    for (int d = 0; d < DD; d++) {
        float x1 = p1[d * SS]; a1 = fmaf(x1, x1, a1);
        float x2 = p2[d * SS]; a2 = fmaf(x2, x2, a2);
    }
    n1[bh * SS + s] = a1;
    n2[bh * SS + s] = a2;
}

// ---------------------------------------------------------------------------
// Kernel 3: attention. One WG per (bh, 8 q-rows). Thread t owns k-columns
// t+256j. e1 scores live in VGPRs; e2 staged in the p_s LDS buffer (idle
// until phase 3). Row max/sum: 64-lane shfl tree + 4-wave LDS combine.
// PV: LDS transpose of normalized p, thread <-> (row, d).
// ---------------------------------------------------------------------------
__global__ __launch_bounds__(256)
void attn_kernel(const float* __restrict__ qg,  const float* __restrict__ k1T,
                 const float* __restrict__ k2T, const float* __restrict__ vg,
                 const float* __restrict__ n1g, const float* __restrict__ n2g,
                 const float* __restrict__ maskg, const float* __restrict__ pig,
                 float* __restrict__ ctx, float* __restrict__ probs)
{
    const float A1C = 0.08838834764831845f;   // SCALING/2 = 1/(2*sqrt(32))
    const float A2C = 0.13258252147247767f;   // 1.5*SCALING/2
    __shared__ float q_s[RQ * DD];            // 1 KB
    __shared__ float p_s[RQ][SS + 4];         // ~32 KB, +4 pad for PV banks
    __shared__ float red_s[4][RQ];
    __shared__ float qn_s[RQ];

    int t    = threadIdx.x;
    int lane = t & 63, wid = t >> 6;
    int bh   = blockIdx.y;
    int b    = bh / HH, h = bh - b * HH;
    int s0   = blockIdx.x * RQ;

    // stage q tile (8 rows x 32, contiguous)
    q_s[t] = qg[(bh * SS + s0) * DD + t];
    __syncthreads();
    if (t < RQ) {
        float a = 0.f;
        for (int d = 0; d < DD; d++) { float x = q_s[t * DD + d]; a = fmaf(x, x, a); }
        qn_s[t] = a;
    }
    __syncthreads();

    float pi0 = clampf(pig[h],      1e-6f, 2.0f);
    float pi1 = clampf(pig[HH + h], 1e-6f, 2.0f);

    float e1r[4][RQ];
    float pm1[RQ], pm2[RQ];
    #pragma unroll
    for (int r = 0; r < RQ; r++) { pm1[r] = -3.4e38f; pm2[r] = -3.4e38f; }

    const float* k1p = k1T + bh * HEAD_ELEMS;
    const float* k2p = k2T + bh * HEAD_ELEMS;
    const float* n1p = n1g + bh * SS;
    const float* n2p = n2g + bh * SS;
    const float* mp  = maskg + b * SS;

    // ---- phase 1: dots + scores -------------------------------------------
    #pragma unroll
    for (int j = 0; j < 4; j++) {
        int k = j * 256 + t;
        float n1k = n1p[k], n2k = n2p[k], mk = mp[k];
        float c1[RQ], c2[RQ];
        #pragma unroll
        for (int r = 0; r < RQ; r++) { c1[r] = 0.f; c2[r] = 0.f; }
        for (int d4 = 0; d4 < 8; d4++) {
            float qv[RQ][4];
            #pragma unroll
            for (int r = 0; r < RQ; r++)
                *(float4*)qv[r] = *(const float4*)&q_s[r * DD + d4 * 4];
            #pragma unroll
            for (int dd = 0; dd < 4; dd++) {
                float kv1 = k1p[(d4 * 4 + dd) * SS + k];
                float kv2 = k2p[(d4 * 4 + dd) * SS + k];
                #pragma unroll
                for (int r = 0; r < RQ; r++) {
                    c1[r] = fmaf(qv[r][dd], kv1, c1[r]);
                    c2[r] = fmaf(qv[r][dd], kv2, c2[r]);
                }
            }
        }
        #pragma unroll
        for (int r = 0; r < RQ; r++) {
            float qn  = qn_s[r];
            float d1v = fmaxf(fmaf(-2.f, c1[r], qn + n1k), 0.f);
            float d2v = fmaxf(fmaf(-2.f, c2[r], qn + n2k), 0.f);
            float ev1 = fmaf(-A1C, d1v, mk);
            float ev2 = fmaf(-A2C, d2v, mk);
            e1r[j][r] = ev1;
            p_s[r][j * 256 + t] = ev2;        // stage e2 in LDS
            pm1[r] = fmaxf(pm1[r], ev1);
            pm2[r] = fmaxf(pm2[r], ev2);
        }
    }

    // ---- row max reductions ------------------------------------------------
    float m1[RQ], m2[RQ];
    #pragma unroll
    for (int off = 32; off >= 1; off >>= 1)
        #pragma unroll
        for (int r = 0; r < RQ; r++) pm1[r] = fmaxf(pm1[r], __shfl_xor(pm1[r], off));
    __syncthreads();
    if (lane == 0) {
        #pragma unroll
        for (int r = 0; r < RQ; r++) red_s[wid][r] = pm1[r];
    }
    __syncthreads();
    #pragma unroll
    for (int r = 0; r < RQ; r++)
        m1[r] = fmaxf(fmaxf(red_s[0][r], red_s[1][r]), fmaxf(red_s[2][r], red_s[3][r]));

    #pragma unroll
    for (int off = 32; off >= 1; off >>= 1)
        #pragma unroll
        for (int r = 0; r < RQ; r++) pm2[r] = fmaxf(pm2[r], __shfl_xor(pm2[r], off));
    __syncthreads();
    if (lane == 0) {
        #pragma unroll
        for (int r = 0; r < RQ; r++) red_s[wid][r] = pm2[r];
    }
    __syncthreads();
    #pragma unroll
    for (int r = 0; r < RQ; r++)
        m2[r] = fmaxf(fmaxf(red_s[0][r], red_s[1][r]), fmaxf(red_s[2][r], red_s[3][r]));

    // ---- phase 2: exp + mixture, row sums ---------------------------------
    float ps[RQ];
    #pragma unroll
    for (int r = 0; r < RQ; r++) ps[r] = 0.f;
    #pragma unroll
    for (int j = 0; j < 4; j++)
        #pragma unroll
        for (int r = 0; r < RQ; r++) {
            float ev2 = p_s[r][j * 256 + t];
            float p = pi0 * __expf(e1r[j][r] - m1[r]) + pi1 * __expf(ev2 - m2[r]);
            e1r[j][r] = p;
            ps[r] += p;
        }

    #pragma unroll
    for (int off = 32; off >= 1; off >>= 1)
        #pragma unroll
        for (int r = 0; r < RQ; r++) ps[r] += __shfl_xor(ps[r], off);
    __syncthreads();
    if (lane == 0) {
        #pragma unroll
        for (int r = 0; r < RQ; r++) red_s[wid][r] = ps[r];
    }
    __syncthreads();
    float inv[RQ];
    #pragma unroll
    for (int r = 0; r < RQ; r++) {
        float sum = red_s[0][r] + red_s[1][r] + red_s[2][r] + red_s[3][r];
        inv[r] = 1.0f / (sum + 1e-6f);
    }

    // ---- phase 3: normalize, write probs (nontemporal), stage p in LDS ----
    float* prow = probs + (size_t)(bh * SS + s0) * SS;
    #pragma unroll
    for (int j = 0; j < 4; j++)
        #pragma unroll
        for (int r = 0; r < RQ; r++) {
            float pn = e1r[j][r] * inv[r];
            p_s[r][j * 256 + t] = pn;
            __builtin_nontemporal_store(pn, &prow[r * SS + j * 256 + t]);
        }
    __syncthreads();

    // ---- phase 4: ctx = probs @ v, thread <-> (row, d) --------------------
    int rr = t >> 5, d = t & 31;
    const float* vp = vg + bh * HEAD_ELEMS + d;
    float acc = 0.f;
    for (int k = 0; k < SS; k += 4) {
        float4 pf = *(const float4*)&p_s[rr][k];
        acc = fmaf(pf.x, vp[(k + 0) * DD], acc);
        acc = fmaf(pf.y, vp[(k + 1) * DD], acc);
        acc = fmaf(pf.z, vp[(k + 2) * DD], acc);
        acc = fmaf(pf.w, vp[(k + 3) * DD], acc);
    }
    ctx[((b * SS + s0 + rr) * HH + h) * DD + d] = acc;
}

// ---------------------------------------------------------------------------
extern "C" void kernel_launch(void* const* d_in, const int* in_sizes, int n_in,
                              void* d_out, int out_size, void* d_ws, size_t ws_size,
                              hipStream_t stream)
{
    const float* hs   = (const float*)d_in[0];
    const float* mask = (const float*)d_in[1];
    const float* Wq   = (const float*)d_in[2];
    const float* bq   = (const float*)d_in[3];
    const float* Wk1  = (const float*)d_in[4];
    const float* bk1  = (const float*)d_in[5];
    const float* Wk2  = (const float*)d_in[6];
    const float* bk2  = (const float*)d_in[7];
    const float* Wv   = (const float*)d_in[8];
    const float* bv   = (const float*)d_in[9];
    const float* pi   = (const float*)d_in[10];

    float* ws   = (float*)d_ws;
    float* q_ws = ws;                       // 1572864 floats
    float* v_ws = ws + (size_t)CTX_ELEMS * 1;
    float* k1T  = ws + (size_t)CTX_ELEMS * 2;
    float* k2T  = ws + (size_t)CTX_ELEMS * 3;
    float* n1   = ws + (size_t)CTX_ELEMS * 4;
    float* n2   = n1 + BB * HH * SS;

    float* ctx   = (float*)d_out;
    float* probs = ctx + CTX_ELEMS;

    proj_kernel<<<dim3(64, 24), 256, 0, stream>>>(hs, Wq, bq, Wk1, bk1, Wk2, bk2,
                                                  Wv, bv, q_ws, k1T, k2T, v_ws);
    norms_kernel<<<dim3(SS / 256, BB * HH), 256, 0, stream>>>(k1T, k2T, n1, n2);
    attn_kernel<<<dim3(SS / RQ, BB * HH), 256, 0, stream>>>(q_ws, k1T, k2T, v_ws,
                                                            n1, n2, mask, pi, ctx, probs);
}

// Round 2
// 674.739 us; speedup vs baseline: 1.4664x; 1.4664x over previous
//
#include <hip/hip_runtime.h>
#include <math.h>

#define BB 4
#define SS 1024
#define HH 12
#define DD 32
#define HIDDEN 768
#define AHS 384
#define RQ 8
#define HEAD_ELEMS (SS*DD)      // 32768
#define CTX_ELEMS (BB*SS*AHS)   // 1572864

__device__ __forceinline__ float clampf(float x, float lo, float hi){ return fminf(fmaxf(x, lo), hi); }

// ---------------------------------------------------------------------------
// Kernel 1: fused QKV projection. C = X @ W^T + b, 4 weight mats as one
// [4096 x 1536] GEMM. 128x64 tile, 8x4 micro-tile, global->reg prefetch.
// q,v stored [BH,S,D]; k1,k2 TRANSPOSED [BH,D,S].
// ---------------------------------------------------------------------------
__global__ __launch_bounds__(256)
void proj_kernel(const float* __restrict__ X,
                 const float* __restrict__ W0, const float* __restrict__ b0,
                 const float* __restrict__ W1, const float* __restrict__ b1,
                 const float* __restrict__ W2, const float* __restrict__ b2,
                 const float* __restrict__ W3, const float* __restrict__ b3,
                 float* __restrict__ qo, float* __restrict__ k1o,
                 float* __restrict__ k2o, float* __restrict__ vo)
{
    const int BM = 128, BN = 64, BK = 16;
    __shared__ float Xs[BK][BM + 4];
    __shared__ float Wsh[BK][BN + 4];
    int t  = threadIdx.x;
    int m0 = blockIdx.x * BM;
    int n0 = blockIdx.y * BN;
    int mat = n0 / AHS;
    int c0  = n0 % AHS;
    const float* W    = (mat==0) ? W0 : (mat==1) ? W1 : (mat==2) ? W2 : W3;
    const float* bias = (mat==0) ? b0 : (mat==1) ? b1 : (mat==2) ? b2 : b3;

    int tx = t & 15, ty = t >> 4;       // micro-tile: rows ty*8..+8, cols tx*4..+4
    int lr = t >> 2;                    // 0..63
    int lc = (t & 3) << 2;              // 0,4,8,12

    float acc[8][4];
    #pragma unroll
    for (int i = 0; i < 8; i++)
        #pragma unroll
        for (int j = 0; j < 4; j++) acc[i][j] = 0.f;

    float4 xa = *(const float4*)(X + (m0 + lr) * HIDDEN + lc);
    float4 xb = *(const float4*)(X + (m0 + 64 + lr) * HIDDEN + lc);
    float4 wa = *(const float4*)(W + (c0 + lr) * HIDDEN + lc);

    for (int k0 = 0; k0 < HIDDEN; k0 += BK) {
        __syncthreads();
        Xs[lc+0][lr] = xa.x; Xs[lc+1][lr] = xa.y; Xs[lc+2][lr] = xa.z; Xs[lc+3][lr] = xa.w;
        Xs[lc+0][64+lr] = xb.x; Xs[lc+1][64+lr] = xb.y; Xs[lc+2][64+lr] = xb.z; Xs[lc+3][64+lr] = xb.w;
        Wsh[lc+0][lr] = wa.x; Wsh[lc+1][lr] = wa.y; Wsh[lc+2][lr] = wa.z; Wsh[lc+3][lr] = wa.w;
        __syncthreads();
        if (k0 + BK < HIDDEN) {   // prefetch next tile during compute
            xa = *(const float4*)(X + (m0 + lr) * HIDDEN + k0 + BK + lc);
            xb = *(const float4*)(X + (m0 + 64 + lr) * HIDDEN + k0 + BK + lc);
            wa = *(const float4*)(W + (c0 + lr) * HIDDEN + k0 + BK + lc);
        }
        #pragma unroll
        for (int kk = 0; kk < BK; kk++) {
            float a[8], w4[4];
            *(float4*)&a[0] = *(const float4*)&Xs[kk][ty << 3];
            *(float4*)&a[4] = *(const float4*)&Xs[kk][(ty << 3) + 4];
            *(float4*)w4    = *(const float4*)&Wsh[kk][tx << 2];
            #pragma unroll
            for (int i = 0; i < 8; i++)
                #pragma unroll
                for (int j = 0; j < 4; j++)
                    acc[i][j] = fmaf(a[i], w4[j], acc[i][j]);
        }
    }

    #pragma unroll
    for (int i = 0; i < 8; i++) {
        int row = m0 + (ty << 3) + i;
        int b_  = row >> 10;
        int s   = row & 1023;
        #pragma unroll
        for (int j = 0; j < 4; j++) {
            int c = c0 + (tx << 2) + j;
            int h = c >> 5, d = c & 31;
            int bh = b_ * HH + h;
            float val = acc[i][j] + bias[c];
            if (mat == 0)      qo [(bh * SS + s) * DD + d] = val;
            else if (mat == 1) k1o[(bh * DD + d) * SS + s] = val;
            else if (mat == 2) k2o[(bh * DD + d) * SS + s] = val;
            else               vo [(bh * SS + s) * DD + d] = val;
        }
    }
}

// ---------------------------------------------------------------------------
// Kernel 2: per-row squared norms of k1,k2 from the transposed layout.
// ---------------------------------------------------------------------------
__global__ __launch_bounds__(256)
void norms_kernel(const float* __restrict__ k1T, const float* __restrict__ k2T,
                  float* __restrict__ n1, float* __restrict__ n2)
{
    int bh = blockIdx.y;
    int s  = blockIdx.x * 256 + threadIdx.x;
    const float* p1 = k1T + bh * HEAD_ELEMS + s;
    const float* p2 = k2T + bh * HEAD_ELEMS + s;
    float a1 = 0.f, a2 = 0.f;
    #pragma unroll
    for (int d = 0; d < DD; d++) {
        float x1 = p1[d * SS]; a1 = fmaf(x1, x1, a1);
        float x2 = p2[d * SS]; a2 = fmaf(x2, x2, a2);
    }
    n1[bh * SS + s] = a1;
    n2[bh * SS + s] = a2;
}

// ---------------------------------------------------------------------------
// Kernel 3: scores + softmax-mixture + probs write. One WG per (bh, 8 rows).
// Both e1,e2 score sets in VGPRs (64 regs); LDS only holds the 8x32 q tile
// and reduction scratch (~1.3 KB) -> occupancy is VGPR-bound, forced to
// 4 waves/SIMD via launch_bounds. q fragments re-read from LDS (broadcast
// b128) instead of pinned in registers to stay under 128 VGPRs.
// ---------------------------------------------------------------------------
__global__ __launch_bounds__(256, 4)
void attn_score(const float* __restrict__ qg,  const float* __restrict__ k1T,
                const float* __restrict__ k2T,
                const float* __restrict__ n1g, const float* __restrict__ n2g,
                const float* __restrict__ maskg, const float* __restrict__ pig,
                float* __restrict__ probs)
{
    const float A1C = 0.08838834764831845f;   // SCALING/2
    const float A2C = 0.13258252147247767f;   // 1.5*SCALING/2
    __shared__ float q_s[RQ * DD];
    __shared__ float red1[4][RQ], red2[4][RQ];
    __shared__ float qn_s[RQ];

    int t    = threadIdx.x;
    int lane = t & 63, wid = t >> 6;
    int bh   = blockIdx.y;
    int b    = bh / HH, h = bh - b * HH;
    int s0   = blockIdx.x * RQ;

    q_s[t] = qg[(bh * SS + s0) * DD + t];
    __syncthreads();
    if (t < RQ) {
        float a = 0.f;
        for (int d = 0; d < DD; d++) { float x = q_s[t * DD + d]; a = fmaf(x, x, a); }
        qn_s[t] = a;
    }
    __syncthreads();

    float pi0 = clampf(pig[h],      1e-6f, 2.0f);
    float pi1 = clampf(pig[HH + h], 1e-6f, 2.0f);

    float e1r[4][RQ], e2r[4][RQ];
    float pm1[RQ], pm2[RQ];
    #pragma unroll
    for (int r = 0; r < RQ; r++) { pm1[r] = -3.4e38f; pm2[r] = -3.4e38f; }

    const float* k1p = k1T + bh * HEAD_ELEMS;
    const float* k2p = k2T + bh * HEAD_ELEMS;
    const float* n1p = n1g + bh * SS;
    const float* n2p = n2g + bh * SS;
    const float* mp  = maskg + b * SS;

    // ---- phase 1: dots + scores -------------------------------------------
    #pragma unroll
    for (int j = 0; j < 4; j++) {
        int k = j * 256 + t;
        float n1k = n1p[k], n2k = n2p[k], mk = mp[k];
        float c1[RQ], c2[RQ];
        #pragma unroll
        for (int r = 0; r < RQ; r++) { c1[r] = 0.f; c2[r] = 0.f; }
        #pragma unroll
        for (int d4 = 0; d4 < 8; d4++) {
            float kv1[4], kv2[4];
            #pragma unroll
            for (int dd = 0; dd < 4; dd++) {
                kv1[dd] = k1p[(d4 * 4 + dd) * SS + k];
                kv2[dd] = k2p[(d4 * 4 + dd) * SS + k];
            }
            #pragma unroll
            for (int r = 0; r < RQ; r++) {
                float qv[4];
                *(float4*)qv = *(const float4*)&q_s[r * DD + d4 * 4];
                #pragma unroll
                for (int dd = 0; dd < 4; dd++) {
                    c1[r] = fmaf(qv[dd], kv1[dd], c1[r]);
                    c2[r] = fmaf(qv[dd], kv2[dd], c2[r]);
                }
            }
        }
        #pragma unroll
        for (int r = 0; r < RQ; r++) {
            float qn  = qn_s[r];
            float d1v = fmaxf(fmaf(-2.f, c1[r], qn + n1k), 0.f);
            float d2v = fmaxf(fmaf(-2.f, c2[r], qn + n2k), 0.f);
            float ev1 = fmaf(-A1C, d1v, mk);
            float ev2 = fmaf(-A2C, d2v, mk);
            e1r[j][r] = ev1;
            e2r[j][r] = ev2;
            pm1[r] = fmaxf(pm1[r], ev1);
            pm2[r] = fmaxf(pm2[r], ev2);
        }
    }

    // ---- row max (both sets, one barrier pair) ----------------------------
    #pragma unroll
    for (int off = 32; off >= 1; off >>= 1)
        #pragma unroll
        for (int r = 0; r < RQ; r++) {
            pm1[r] = fmaxf(pm1[r], __shfl_xor(pm1[r], off));
            pm2[r] = fmaxf(pm2[r], __shfl_xor(pm2[r], off));
        }
    if (lane == 0) {
        #pragma unroll
        for (int r = 0; r < RQ; r++) { red1[wid][r] = pm1[r]; red2[wid][r] = pm2[r]; }
    }
    __syncthreads();
    float m1[RQ], m2[RQ];
    #pragma unroll
    for (int r = 0; r < RQ; r++) {
        m1[r] = fmaxf(fmaxf(red1[0][r], red1[1][r]), fmaxf(red1[2][r], red1[3][r]));
        m2[r] = fmaxf(fmaxf(red2[0][r], red2[1][r]), fmaxf(red2[2][r], red2[3][r]));
    }

    // ---- phase 2: exp + mixture, row sums ---------------------------------
    float ps[RQ];
    #pragma unroll
    for (int r = 0; r < RQ; r++) ps[r] = 0.f;
    #pragma unroll
    for (int j = 0; j < 4; j++)
        #pragma unroll
        for (int r = 0; r < RQ; r++) {
            float p = pi0 * __expf(e1r[j][r] - m1[r]) + pi1 * __expf(e2r[j][r] - m2[r]);
            e1r[j][r] = p;
            ps[r] += p;
        }

    #pragma unroll
    for (int off = 32; off >= 1; off >>= 1)
        #pragma unroll
        for (int r = 0; r < RQ; r++) ps[r] += __shfl_xor(ps[r], off);
    __syncthreads();
    if (lane == 0) {
        #pragma unroll
        for (int r = 0; r < RQ; r++) red1[wid][r] = ps[r];
    }
    __syncthreads();
    float inv[RQ];
    #pragma unroll
    for (int r = 0; r < RQ; r++) {
        float sum = red1[0][r] + red1[1][r] + red1[2][r] + red1[3][r];
        inv[r] = 1.0f / (sum + 1e-6f);
    }

    // ---- phase 3: normalize + write probs (keep in L2/L3 for pv) ----------
    float* prow = probs + (size_t)(bh * SS + s0) * SS;
    #pragma unroll
    for (int j = 0; j < 4; j++)
        #pragma unroll
        for (int r = 0; r < RQ; r++)
            prow[(size_t)r * SS + j * 256 + t] = e1r[j][r] * inv[r];
}

// ---------------------------------------------------------------------------
// Kernel 4: ctx = probs @ v. One WG per (bh, 32 rows). p chunk staged in LDS
// (32x64, 8.5 KB); thread = (row, d4) with float4 v loads and float4 ctx
// stores.
// ---------------------------------------------------------------------------
__global__ __launch_bounds__(256)
void pv_kernel(const float* __restrict__ probs, const float* __restrict__ vg,
               float* __restrict__ ctx)
{
    __shared__ float p_s[32][68];
    int t  = threadIdx.x;
    int bh = blockIdx.y;
    int b  = bh / HH, h = bh - b * HH;
    int r0 = blockIdx.x * 32;
    int rr = t >> 3;         // 0..31
    int d4 = t & 7;          // float4 group

    const float* prow = probs + (size_t)(bh * SS + r0) * SS;
    const float* vp   = vg + bh * HEAD_ELEMS;
    float4 acc = {0.f, 0.f, 0.f, 0.f};

    for (int c = 0; c < SS; c += 64) {
        __syncthreads();
        #pragma unroll
        for (int i = 0; i < 8; i++) {
            int idx = i * 256 + t;
            int row = idx >> 6, col = idx & 63;
            p_s[row][col] = prow[(size_t)row * SS + c + col];
        }
        __syncthreads();
        #pragma unroll
        for (int kk = 0; kk < 64; kk++) {
            float p = p_s[rr][kk];
            float4 vv = *(const float4*)&vp[(c + kk) * DD + d4 * 4];
            acc.x = fmaf(p, vv.x, acc.x);
            acc.y = fmaf(p, vv.y, acc.y);
            acc.z = fmaf(p, vv.z, acc.z);
            acc.w = fmaf(p, vv.w, acc.w);
        }
    }
    *(float4*)&ctx[((size_t)(b * SS + r0 + rr) * HH + h) * DD + d4 * 4] = acc;
}

// ---------------------------------------------------------------------------
extern "C" void kernel_launch(void* const* d_in, const int* in_sizes, int n_in,
                              void* d_out, int out_size, void* d_ws, size_t ws_size,
                              hipStream_t stream)
{
    const float* hs   = (const float*)d_in[0];
    const float* mask = (const float*)d_in[1];
    const float* Wq   = (const float*)d_in[2];
    const float* bq   = (const float*)d_in[3];
    const float* Wk1  = (const float*)d_in[4];
    const float* bk1  = (const float*)d_in[5];
    const float* Wk2  = (const float*)d_in[6];
    const float* bk2  = (const float*)d_in[7];
    const float* Wv   = (const float*)d_in[8];
    const float* bv   = (const float*)d_in[9];
    const float* pi   = (const float*)d_in[10];

    float* ws   = (float*)d_ws;
    float* q_ws = ws;
    float* v_ws = ws + (size_t)CTX_ELEMS * 1;
    float* k1T  = ws + (size_t)CTX_ELEMS * 2;
    float* k2T  = ws + (size_t)CTX_ELEMS * 3;
    float* n1   = ws + (size_t)CTX_ELEMS * 4;
    float* n2   = n1 + BB * HH * SS;

    float* ctx   = (float*)d_out;
    float* probs = ctx + CTX_ELEMS;

    proj_kernel<<<dim3(32, 24), 256, 0, stream>>>(hs, Wq, bq, Wk1, bk1, Wk2, bk2,
                                                  Wv, bv, q_ws, k1T, k2T, v_ws);
    norms_kernel<<<dim3(SS / 256, BB * HH), 256, 0, stream>>>(k1T, k2T, n1, n2);
    attn_score<<<dim3(SS / RQ, BB * HH), 256, 0, stream>>>(q_ws, k1T, k2T,
                                                           n1, n2, mask, pi, probs);
    pv_kernel<<<dim3(SS / 32, BB * HH), 256, 0, stream>>>(probs, v_ws, ctx);
}